// Round 19
// baseline (129.698 us; speedup 1.0000x reference)
//
#include <hip/hip_runtime.h>
#include <stdint.h>

#define C      1024
#define NH     16
#define HS     64
#define CT     65536
#define PAST   61440   // CT - WINDOW
#define KEEP   12288   // MIN_KV - WINDOW
#define NCOMP  192     // KEEP/64
#define NSEL   32
#define NB     8192    // selection bins (fixed-range; partition-invariant)
#define NBLK   256     // mega-kernel grid (1 block/CU, co-resident)
#define FLAGW  8       // u32 stride between per-block flags (32 B lines)

typedef unsigned long long ull;

// agent-scope relaxed accessors: write-through / fresh-read at coherence point
#define LD_A(p)   __hip_atomic_load((p), __ATOMIC_RELAXED, __HIP_MEMORY_SCOPE_AGENT)
#define ST_A(p,v) __hip_atomic_store((p), (v), __ATOMIC_RELAXED, __HIP_MEMORY_SCOPE_AGENT)

// monotone transform: larger float => smaller u (asc u == desc value)
__device__ __forceinline__ unsigned int desc_key(float f) {
    unsigned int b = __float_as_uint(f);
    return (b >> 31) ? b : (~b & 0x7FFFFFFFu);
}
__device__ __forceinline__ float u_to_f(unsigned int u) {
    unsigned int b = (u & 0x80000000u) ? u : (0x7FFFFFFFu - u);
    return __uint_as_float(b);
}
// FIXED monotone linear bin: s in [-64,64] (scores ~ N(0,8^2); clamp is still
// exact — within-bin compare resolves any bin's contents precisely)
__device__ __forceinline__ int bin_of(float s) {
    int b = (int)((64.f - s) * (8191.f / 128.f));
    return b < 0 ? 0 : (b > NB - 1 ? NB - 1 : b);
}

// store-based sense barriers (validated R13-R16): arrival = one scoped STORE to
// the block's own padded flag line; wait = parallel polls. Flags monotone 1..5.
__device__ __forceinline__ void arrive(unsigned* flag, unsigned ph) {
    __syncthreads();
    if (threadIdx.x == 0) {
        asm volatile("s_waitcnt vmcnt(0)" ::: "memory");
        ST_A(&flag[blockIdx.x * FLAGW], ph);
    }
}
__device__ __forceinline__ void wait_head(unsigned* flag, unsigned ph, int h) {
    if (threadIdx.x < 16)
        while (LD_A(&flag[(h * 16 + threadIdx.x) * FLAGW]) < ph)
            __builtin_amdgcn_s_sleep(2);
    __syncthreads();
}
__device__ __forceinline__ void wait_all(unsigned* flag, unsigned ph) {
    if (threadIdx.x < NBLK)
        while (LD_A(&flag[threadIdx.x * FLAGW]) < ph)
            __builtin_amdgcn_s_sleep(2);
    __syncthreads();
}

// ---------------- K1: q/k/v projections + all zero-inits ---------------------
__global__ void k_proj(const float* __restrict__ x, const float* __restrict__ Wr,
                       const float* __restrict__ Wk, const float* __restrict__ Wv,
                       float* __restrict__ q, float* __restrict__ kn, float* __restrict__ vn,
                       unsigned* __restrict__ hc, ull* __restrict__ cs_fix,
                       unsigned* __restrict__ flag) {
    int gid = blockIdx.x * 256 + threadIdx.x;       // 0..196607
    for (int i = gid; i < 2 * NH * NB; i += 196608) hc[i] = 0;   // hist + cnt
    if (blockIdx.x >= 512 && blockIdx.x < 520)
        flag[(blockIdx.x - 512) * 256 + threadIdx.x] = 0u;       // 2048 u32
    if (blockIdx.x == 701 && threadIdx.x < 256) cs_fix[threadIdx.x] = 0ull;

    int w = blockIdx.x * (blockDim.x >> 6) + (threadIdx.x >> 6); // 0..3071
    int lane = threadIdx.x & 63;
    int mat = w >> 10, row = w & 1023;
    const float* W = (mat == 0) ? Wr : (mat == 1) ? Wk : Wv;
    const float4* Wrow = (const float4*)(W + (size_t)row * C);
    const float4* x4 = (const float4*)x;
    float acc = 0.f;
#pragma unroll
    for (int i = 0; i < 4; ++i) {
        float4 a = Wrow[i * 64 + lane];
        float4 b = x4[i * 64 + lane];
        acc += a.x * b.x + a.y * b.y + a.z * b.z + a.w * b.w;
    }
#pragma unroll
    for (int off = 32; off; off >>= 1) acc += __shfl_xor(acc, off);
    if (lane == 0) { (mat == 0 ? q : (mat == 1 ? kn : vn))[row] = acc; }
}

// ---- K2 (mega): per-head scores -> hist -> scan+scatter -> rank -> attn -> out
__global__ __launch_bounds__(1024, 2) void k_mega(
        const float* __restrict__ kc, const float* __restrict__ vc,
        unsigned* __restrict__ hist, unsigned* __restrict__ cnt,
        ull* __restrict__ G, ull* __restrict__ stokv,
        ull* __restrict__ cs_fix, float* __restrict__ part,
        const float* __restrict__ q, const float* __restrict__ kn,
        const float* __restrict__ vn, const float* __restrict__ Wo,
        float* __restrict__ yg, float* __restrict__ out,
        float* __restrict__ s_win, unsigned* __restrict__ flag) {
    const int bid = blockIdx.x, tid = threadIdx.x;
    const int lane = tid & 63, wave = tid >> 6;
    const int h = bid >> 4, seg = bid & 15;
    __shared__ __align__(16) char smem[50688];
    __shared__ unsigned shT, shN;
    __shared__ unsigned wsum[16];

    float* s_lds = (float*)smem;                // 16 KB: this block's 4096 scores
    unsigned* lh = (unsigned*)(smem + 16384);   // 32 KB: hist, then scan bases

    // ---- Phase B: scores s[h][seg*4096 + i] for i in [0,4096); own head only
    {
        const int t_base = seg * 4096;
        const int g = lane >> 4;                 // 16-lane group 0..3
        float4 qv = ((const float4*)q)[h * 16 + (lane & 15)];
        for (int ib = 0; ib < 64; ib += 4) {     // 4-token-batch x 4 groups
            float4 av[4];
#pragma unroll
            for (int u = 0; u < 4; ++u) {
                int lt = wave * 256 + (ib + u) * 4 + g;
                av[u] = ((const float4*)(kc + (size_t)(t_base + lt) * C + h * HS))[lane & 15];
            }
#pragma unroll
            for (int u = 0; u < 4; ++u) {
                float d = av[u].x * qv.x + av[u].y * qv.y + av[u].z * qv.z + av[u].w * qv.w;
#pragma unroll
                for (int off = 8; off; off >>= 1) d += __shfl_xor(d, off);
                int lt = wave * 256 + (ib + u) * 4 + g;
                if ((lane & 15) == 0) s_lds[lt] = d;
            }
        }
        __syncthreads();
        if (seg == 15) {                         // window: s_win + chunk sums
            for (int i = tid; i < 4096; i += 1024)
                ST_A(&s_win[h * 4096 + i], s_lds[i]);
            int c = tid >> 4;                    // 64 chunks x 16 threads
            long long f = 0;
#pragma unroll
            for (int j = 0; j < 4; ++j)
                f += llrintf(s_lds[c * 64 + (tid & 15) * 4 + j] * 16777216.f);
#pragma unroll
            for (int off = 8; off; off >>= 1) f += __shfl_xor(f, off);
            if ((tid & 15) == 0) atomicAdd(&cs_fix[NCOMP + c], (ull)f);
        }
    }

    // ---- Phase C: local histogram (segs 0-14) -> global flush (no pre-barrier:
    // bin params are compile-time constants; only our own s_lds is needed)
    {
        for (int i = tid; i < NB; i += 1024) lh[i] = 0;
        __syncthreads();
        if (seg < 15) {
            for (int i = tid; i < 4096; i += 1024)
                atomicAdd(&lh[bin_of(s_lds[i])], 1u);
            __syncthreads();
            unsigned* gh = hist + h * NB;
            for (int i = tid; i < NB; i += 1024) {
                unsigned c = lh[i];
                if (c) atomicAdd(&gh[i], c);
            }
        }
    }
    arrive(flag, 1); wait_head(flag, 1, h);

    // ---- Scan (redundant in every block): lh = exclusive bases; T, ncand
    {
        const unsigned* gh = hist + h * NB;
        unsigned c8[8]; unsigned loc = 0; int b0 = tid * 8;
#pragma unroll
        for (int k = 0; k < 8; ++k) { c8[k] = gh[b0 + k]; loc += c8[k]; }
        unsigned run = loc;
#pragma unroll
        for (int off = 1; off < 64; off <<= 1) {
            unsigned n = __shfl_up(run, off);
            if (lane >= off) run += n;
        }
        if (lane == 63) wsum[wave] = run;
        __syncthreads();
        if (wave == 0 && lane < 16) {
            unsigned v = wsum[lane];
#pragma unroll
            for (int off = 1; off < 16; off <<= 1) {
                unsigned n = __shfl_up(v, off);
                if (lane >= off) v += n;
            }
            wsum[lane] = v;
        }
        __syncthreads();
        unsigned r = run - loc + (wave ? wsum[wave - 1] : 0u);
#pragma unroll
        for (int k = 0; k < 8; ++k) {
            unsigned c = c8[k];
            lh[b0 + k] = r;
            unsigned inc = r + c;
            if (r < KEEP && inc >= KEEP) { shT = (unsigned)(b0 + k); shN = inc; }
            r = inc;
        }
    }
    __syncthreads();
    const unsigned T = shT, ncand = shN;

    // ---- Scatter from LDS scores: pos = lds_base[b] + ticket(cnt)
    if (seg < 15) {
        unsigned* ch = cnt + h * NB;
        ull* Gh = G + (size_t)h * 65536;
        const int t_base = seg * 4096;
        for (int i = tid; i < 4096; i += 1024) {
            float v = s_lds[i];
            int b = bin_of(v);
            if ((unsigned)b <= T) {
                unsigned pos = lh[b] + atomicAdd(&ch[b], 1u);
                ST_A(&Gh[pos], ((ull)desc_key(v) << 16) | (unsigned)(t_base + i));
            }
        }
    }
    arrive(flag, 2); wait_head(flag, 2, h);

    // ---- Phase F: exact rank (static bin bounds from LDS scan); store packed
    {
        ull* csl = (ull*)(smem + 49152);        // 1.5 KB, after lh
        if (tid < NCOMP) csl[tid] = 0ull;
        __syncthreads();
        const ull* Gh = G + (size_t)h * 65536;
        for (unsigned p = seg * 1024 + tid; p < ncand; p += 16384) {
            ull pk = Gh[p];
            unsigned u = (unsigned)(pk >> 16);
            float v = u_to_f(u);
            int b = bin_of(v);
            unsigned start = lh[b];
            unsigned end = (b == NB - 1) ? ncand : lh[b + 1];
            unsigned rank = start;
            for (unsigned j = start; j < end; ++j) rank += (Gh[j] < pk) ? 1u : 0u;
            if (rank < KEEP) {
                ST_A(&stokv[h * KEEP + rank], pk);
                long long f = llrintf(v * 16777216.f);
                atomicAdd(&csl[rank >> 6], (ull)f);
            }
        }
        __syncthreads();
        if (tid < NCOMP) {
            ull c = csl[tid];
            if (c) atomicAdd(&cs_fix[tid], c);
        }
    }
    arrive(flag, 3); wait_all(flag, 3);

    // ---- Phase H: top-32 (redundant/block) + partial softmax+PV (2 pairs/blk)
    {
        ull* key = (ull*)smem;                       // 2048 B
        unsigned* sel_l = (unsigned*)(smem + 2048);  // 128 B
        float* scm = (float*)(smem + 2176);          // 512 B (2x64)
        float* exb = (float*)(smem + 2688);          // 512 B (2x64)
        float* vbuf = (float*)(smem + 3200);         // 2 x 64 x 68 floats
        if (tid < 256) {
            long long v = (long long)cs_fix[tid];    // plain: first touch post-F
            ull bb = (ull)(v + (1ll << 45));
            key[tid] = (((1ull << 46) - bb) << 8) | (unsigned)tid;
        }
        __syncthreads();
        for (unsigned k = 2; k <= 256; k <<= 1) {
            for (unsigned j = k >> 1; j > 0; j >>= 1) {
                if (tid < 256) {
                    unsigned ixj = tid ^ j;
                    if (ixj > (unsigned)tid) {
                        ull a = key[tid], b = key[ixj];
                        bool up = ((tid & k) == 0);
                        if (up ? (a > b) : (a < b)) { key[tid] = b; key[ixj] = a; }
                    }
                }
                __syncthreads();
            }
        }
        if (tid < NSEL) sel_l[tid] = (unsigned)(key[tid] & 0xFFull);
        __syncthreads();

        int su = tid >> 9, sid = tid & 511;
        int p = bid * 2 + su;                    // 0..511; hh == bid>>4 == h
        int hh = p >> 5, ci = p & 31;
        int c = (int)sel_l[ci];
        int g = sid >> 3, q8 = sid & 7;
        int t; float sv;
        if (c < NCOMP) {
            ull pk = stokv[hh * KEEP + c * 64 + g];   // plain: head-local
            t = (int)(pk & 0xFFFFull);
            sv = u_to_f((unsigned)(pk >> 16));
        } else {
            int j = (c - NCOMP) * 64 + g;
            t = PAST + j;
            sv = s_win[hh * 4096 + j];                // plain: first touch
        }
        if (q8 == 0) scm[su * 64 + g] = sv * 0.125f;
        __syncthreads();
        float m = -1e30f;
        for (int j = 0; j < 64; ++j) m = fmaxf(m, scm[su * 64 + j]);
        float e = expf(scm[su * 64 + g] - m);
        if (q8 == 0) exb[su * 64 + g] = e;
        const float4* vrow = (const float4*)(vc + (size_t)t * C + hh * HS);
        float4 v0 = vrow[q8 * 2], v1 = vrow[q8 * 2 + 1];
        float* vb = vbuf + su * 4352 + g * 68 + q8 * 8;
        vb[0] = e * v0.x; vb[1] = e * v0.y; vb[2] = e * v0.z; vb[3] = e * v0.w;
        vb[4] = e * v1.x; vb[5] = e * v1.y; vb[6] = e * v1.z; vb[7] = e * v1.w;
        __syncthreads();
        if (sid < 64) {
            float acc = 0.f;
            for (int g2 = 0; g2 < 64; ++g2) acc += vbuf[su * 4352 + g2 * 68 + sid];
            float* P = part + (size_t)(hh * 32 + ci) * 68;
            ST_A(&P[2 + sid], acc);
            if (sid == 0) {
                float es = 0.f;
                for (int g2 = 0; g2 < 64; ++g2) es += exb[su * 64 + g2];
                ST_A(&P[0], m);
                ST_A(&P[1], es);
            }
        }
    }
    arrive(flag, 4); wait_head(flag, 4, h);

    // ---- Wo prefetch (independent of y) hides under the y barrier
    int row = bid * 4 + (wave >> 2), qtr = wave & 3;
    const float4* Wrow4 = (const float4*)(Wo + (size_t)row * C) + qtr * 64;
    float4 wa = Wrow4[lane];

    // ---- y[h]: combined once per head (seg 0), 64 lanes
    if (seg == 0 && tid < 64) {
        float p = q[h * 64 + tid] * kn[h * 64 + tid];
#pragma unroll
        for (int off = 32; off; off >>= 1) p += __shfl_xor(p, off);
        float a_new = p * 0.125f;
        const float* P0 = part + (size_t)h * 32 * 68;   // plain: head-local
        float m = a_new;
        for (int ci = 0; ci < 32; ++ci) m = fmaxf(m, P0[ci * 68]);
        float den = expf(a_new - m);
        float acc = den * vn[h * HS + tid];
        for (int ci = 0; ci < 32; ++ci) {
            float w = expf(P0[ci * 68] - m);
            den += w * P0[ci * 68 + 1];
            acc += w * P0[ci * 68 + 2 + tid];
        }
        ST_A(&yg[h * HS + tid], acc / den);
    }
    if (seg == 0) arrive(flag, 5);             // only y-writers publish phase 5
    if (tid < 16)
        while (LD_A(&flag[(tid * 16) * FLAGW]) < 5u) __builtin_amdgcn_s_sleep(2);
    __syncthreads();

    // ---- Wo matmul: block bid -> rows [bid*4, bid*4+4), wave = (row, quarter)
    {
        float* yl = (float*)smem;                 // 4 KB
        float* ps = (float*)(smem + 4096);        // 64 B
        yl[tid] = yg[tid];                        // plain: first touch this block
        __syncthreads();
        const float4* y4 = (const float4*)yl + qtr * 64;
        float4 b = y4[lane];
        float acc = wa.x * b.x + wa.y * b.y + wa.z * b.z + wa.w * b.w;
#pragma unroll
        for (int off = 32; off; off >>= 1) acc += __shfl_xor(acc, off);
        if (lane == 0) ps[wave] = acc;
        __syncthreads();
        if (tid < 4)
            out[bid * 4 + tid] = ps[tid * 4] + ps[tid * 4 + 1] + ps[tid * 4 + 2] + ps[tid * 4 + 3];
    }
}

extern "C" void kernel_launch(void* const* d_in, const int* in_sizes, int n_in,
                              void* d_out, int out_size, void* d_ws, size_t ws_size,
                              hipStream_t stream) {
    const float* x  = (const float*)d_in[0];
    const float* kc = (const float*)d_in[1];
    const float* vc = (const float*)d_in[2];
    const float* Wr = (const float*)d_in[3];
    const float* Wk = (const float*)d_in[4];
    const float* Wv = (const float*)d_in[5];
    const float* Wo = (const float*)d_in[6];
    float* out = (float*)d_out;
    char* ws = (char*)d_ws;

    float* q    = (float*)(ws + 0);
    float* kn   = (float*)(ws + 8192);
    float* vn   = (float*)(ws + 16384);
    ull* cs_fix = (ull*)(ws + 32768);                  // 2 KiB
    float* yg   = (float*)(ws + 40960);                // 4 KiB
    float* part = (float*)(ws + 49152);                // 139264 B -> ends 188416
    unsigned* flag = (unsigned*)(ws + 192512);         // 8 KiB (256 x 32B)
    float* s_win   = (float*)(ws + 262144);            // 256 KiB -> ends 524288
    ull* stokv     = (ull*)(ws + 524288);              // 1.5 MiB -> ends 2097152
    unsigned* hist = (unsigned*)(ws + 2097152);        // 512 KiB
    unsigned* cnt  = (unsigned*)(ws + 2621440);        // 512 KiB (contiguous after hist)
    ull* G = (ull*)(ws + 3145728);                     // 8 MiB

    k_proj<<<768, 256, 0, stream>>>(x, Wr, Wk, Wv, q, kn, vn, hist, cs_fix, flag);
    k_mega<<<NBLK, 1024, 0, stream>>>(kc, vc, hist, cnt, G, stokv, cs_fix,
                                      part, q, kn, vn, Wo, yg, out, s_win, flag);
}

// Round 20
// 115.781 us; speedup vs baseline: 1.1202x; 1.1202x over previous
//
#include <hip/hip_runtime.h>
#include <stdint.h>

#define C      1024
#define NH     16
#define HS     64
#define CT     65536
#define PAST   61440   // CT - WINDOW
#define KEEP   12288   // MIN_KV - WINDOW
#define NCOMP  192     // KEEP/64
#define NSEL   32
#define NB     8192    // selection bins
#define NBLK   256     // mega-kernel grid (1 block/CU, co-resident)
#define FLAGW  8       // u32 stride between per-block flags (32 B lines)

typedef unsigned long long ull;

// agent-scope relaxed accessors: write-through / fresh-read at coherence point
#define LD_A(p)   __hip_atomic_load((p), __ATOMIC_RELAXED, __HIP_MEMORY_SCOPE_AGENT)
#define ST_A(p,v) __hip_atomic_store((p), (v), __ATOMIC_RELAXED, __HIP_MEMORY_SCOPE_AGENT)

// monotone transform: larger float => smaller u (asc u == desc value)
__device__ __forceinline__ unsigned int desc_key(float f) {
    unsigned int b = __float_as_uint(f);
    return (b >> 31) ? b : (~b & 0x7FFFFFFFu);
}
__device__ __forceinline__ float u_to_f(unsigned int u) {
    unsigned int b = (u & 0x80000000u) ? u : (0x7FFFFFFFu - u);
    return __uint_as_float(b);
}
// monotone linear bin: s descending <-> bin ascending
__device__ __forceinline__ int bin_of(float s, float hi, float scale) {
    int b = (int)((hi - s) * scale);
    return b < 0 ? 0 : (b > NB - 1 ? NB - 1 : b);
}
__device__ __forceinline__ void load_params(const unsigned* umin, const unsigned* umax,
                                            int h, float* hi, float* sc) {
    float h2 = u_to_f(umin[h]);
    float lo = u_to_f(umax[h]);
    float r = h2 - lo;
    *hi = h2;
    *sc = (r > 0.f) ? (float)(NB - 1) / r : 0.f;
}

// store-based sense barriers (validated R13-R16): arrival = one scoped STORE to
// the block's own padded flag line; wait = parallel polls. Flags monotone 1..6.
__device__ __forceinline__ void arrive(unsigned* flag, unsigned ph) {
    __syncthreads();
    if (threadIdx.x == 0) {
        asm volatile("s_waitcnt vmcnt(0)" ::: "memory");
        ST_A(&flag[blockIdx.x * FLAGW], ph);
    }
}
__device__ __forceinline__ void wait_head(unsigned* flag, unsigned ph, int h) {
    if (threadIdx.x < 16)
        while (LD_A(&flag[(h * 16 + threadIdx.x) * FLAGW]) < ph)
            __builtin_amdgcn_s_sleep(2);
    __syncthreads();
}
__device__ __forceinline__ void wait_all(unsigned* flag, unsigned ph) {
    if (threadIdx.x < NBLK)
        while (LD_A(&flag[threadIdx.x * FLAGW]) < ph)
            __builtin_amdgcn_s_sleep(2);
    __syncthreads();
}

// ---------------- K1: q/k/v projections + all zero-inits ---------------------
__global__ void k_proj(const float* __restrict__ x, const float* __restrict__ Wr,
                       const float* __restrict__ Wk, const float* __restrict__ Wv,
                       float* __restrict__ q, float* __restrict__ kn, float* __restrict__ vn,
                       unsigned* __restrict__ hc, unsigned* __restrict__ umin,
                       unsigned* __restrict__ umax, ull* __restrict__ cs_fix,
                       unsigned* __restrict__ flag) {
    int gid = blockIdx.x * 256 + threadIdx.x;       // 0..196607
    for (int i = gid; i < 2 * NH * NB; i += 196608) hc[i] = 0;   // hist + cnt
    if (blockIdx.x >= 512 && blockIdx.x < 520)
        flag[(blockIdx.x - 512) * 256 + threadIdx.x] = 0u;       // 2048 u32
    if (blockIdx.x == 700) {
        if (threadIdx.x < 16) umin[threadIdx.x] = 0xFFFFFFFFu;
        else if (threadIdx.x < 32) umax[threadIdx.x - 16] = 0u;
    }
    if (blockIdx.x == 701 && threadIdx.x < 256) cs_fix[threadIdx.x] = 0ull;

    int w = blockIdx.x * (blockDim.x >> 6) + (threadIdx.x >> 6); // 0..3071
    int lane = threadIdx.x & 63;
    int mat = w >> 10, row = w & 1023;
    const float* W = (mat == 0) ? Wr : (mat == 1) ? Wk : Wv;
    const float4* Wrow = (const float4*)(W + (size_t)row * C);
    const float4* x4 = (const float4*)x;
    float acc = 0.f;
#pragma unroll
    for (int i = 0; i < 4; ++i) {
        float4 a = Wrow[i * 64 + lane];
        float4 b = x4[i * 64 + lane];
        acc += a.x * b.x + a.y * b.y + a.z * b.z + a.w * b.w;
    }
#pragma unroll
    for (int off = 32; off; off >>= 1) acc += __shfl_xor(acc, off);
    if (lane == 0) { (mat == 0 ? q : (mat == 1 ? kn : vn))[row] = acc; }
}

// ---- K2 (mega): per-head scores -> hist -> scan+scatter -> rank -> attn -> out
__global__ __launch_bounds__(1024, 2) void k_mega(
        const float* __restrict__ kc, const float* __restrict__ vc,
        unsigned* __restrict__ umin, unsigned* __restrict__ umax,
        unsigned* __restrict__ hist, unsigned* __restrict__ cnt,
        ull* __restrict__ G, ull* __restrict__ stokv,
        ull* __restrict__ cs_fix, float* __restrict__ part,
        const float* __restrict__ q, const float* __restrict__ kn,
        const float* __restrict__ vn, const float* __restrict__ Wo,
        float* __restrict__ yg, float* __restrict__ out,
        float* __restrict__ s_win, unsigned* __restrict__ flag) {
    const int bid = blockIdx.x, tid = threadIdx.x;
    const int lane = tid & 63, wave = tid >> 6;
    const int h = bid >> 4, seg = bid & 15;
    __shared__ __align__(16) char smem[50688];
    __shared__ unsigned shT, shN;
    __shared__ unsigned wsum[16];
    __shared__ float smn[16], smx[16];

    float* s_lds = (float*)smem;                // 16 KB: this block's 4096 scores
    unsigned* lh = (unsigned*)(smem + 16384);   // 32 KB: hist, then scan bases

    // ---- Phase B: scores s[h][seg*4096 + i] for i in [0,4096); own head only
    {
        const int t_base = seg * 4096;
        const int g = lane >> 4;                 // 16-lane group 0..3
        float4 qv = ((const float4*)q)[h * 16 + (lane & 15)];
        float mn = 3.4e38f, mx = -3.4e38f;
        for (int ib = 0; ib < 64; ib += 4) {     // 4-token-batch x 4 groups
            float4 av[4];
#pragma unroll
            for (int u = 0; u < 4; ++u) {
                int lt = wave * 256 + (ib + u) * 4 + g;
                av[u] = ((const float4*)(kc + (size_t)(t_base + lt) * C + h * HS))[lane & 15];
            }
#pragma unroll
            for (int u = 0; u < 4; ++u) {
                float d = av[u].x * qv.x + av[u].y * qv.y + av[u].z * qv.z + av[u].w * qv.w;
#pragma unroll
                for (int off = 8; off; off >>= 1) d += __shfl_xor(d, off);
                int lt = wave * 256 + (ib + u) * 4 + g;
                if ((lane & 15) == 0) s_lds[lt] = d;
                mn = fminf(mn, d);
                mx = fmaxf(mx, d);
            }
        }
        __syncthreads();
        if (seg < 15) {                          // PAST: per-head min/max
#pragma unroll
            for (int off = 32; off; off >>= 1) {
                mn = fminf(mn, __shfl_xor(mn, off));
                mx = fmaxf(mx, __shfl_xor(mx, off));
            }
            if (lane == 0) { smn[wave] = mn; smx[wave] = mx; }
            __syncthreads();
            if (tid == 0) {
                float bmn = smn[0], bmx = smx[0];
                for (int w2 = 1; w2 < 16; ++w2) {
                    bmn = fminf(bmn, smn[w2]);
                    bmx = fmaxf(bmx, smx[w2]);
                }
                atomicMin(&umin[h], desc_key(bmx));
                atomicMax(&umax[h], desc_key(bmn));
            }
        } else {                                 // window: s_win + chunk sums
            for (int i = tid; i < 4096; i += 1024)
                ST_A(&s_win[h * 4096 + i], s_lds[i]);
            int c = tid >> 4;                    // 64 chunks x 16 threads
            long long f = 0;
#pragma unroll
            for (int j = 0; j < 4; ++j)
                f += llrintf(s_lds[c * 64 + (tid & 15) * 4 + j] * 16777216.f);
#pragma unroll
            for (int off = 8; off; off >>= 1) f += __shfl_xor(f, off);
            if ((tid & 15) == 0) atomicAdd(&cs_fix[NCOMP + c], (ull)f);
        }
    }
    arrive(flag, 1); wait_head(flag, 1, h);

    float hi, sc; load_params(umin, umax, h, &hi, &sc);

    // ---- Phase C: histogram (segs 0-14; LDS hist -> device atomicAdd)
    {
        for (int i = tid; i < NB; i += 1024) lh[i] = 0;
        __syncthreads();
        if (seg < 15) {
            for (int i = tid; i < 4096; i += 1024)
                atomicAdd(&lh[bin_of(s_lds[i], hi, sc)], 1u);
            __syncthreads();
            unsigned* gh = hist + h * NB;
            for (int i = tid; i < NB; i += 1024) {
                unsigned c = lh[i];
                if (c) atomicAdd(&gh[i], c);
            }
        }
    }
    arrive(flag, 2); wait_head(flag, 2, h);

    // ---- Scan (redundant in every block): lh = exclusive bases; T, ncand
    {
        const unsigned* gh = hist + h * NB;
        unsigned c8[8]; unsigned loc = 0; int b0 = tid * 8;
#pragma unroll
        for (int k = 0; k < 8; ++k) { c8[k] = gh[b0 + k]; loc += c8[k]; }
        unsigned run = loc;
#pragma unroll
        for (int off = 1; off < 64; off <<= 1) {
            unsigned n = __shfl_up(run, off);
            if (lane >= off) run += n;
        }
        if (lane == 63) wsum[wave] = run;
        __syncthreads();
        if (wave == 0 && lane < 16) {
            unsigned v = wsum[lane];
#pragma unroll
            for (int off = 1; off < 16; off <<= 1) {
                unsigned n = __shfl_up(v, off);
                if (lane >= off) v += n;
            }
            wsum[lane] = v;
        }
        __syncthreads();
        unsigned r = run - loc + (wave ? wsum[wave - 1] : 0u);
#pragma unroll
        for (int k = 0; k < 8; ++k) {
            unsigned c = c8[k];
            lh[b0 + k] = r;
            unsigned inc = r + c;
            if (r < KEEP && inc >= KEEP) { shT = (unsigned)(b0 + k); shN = inc; }
            r = inc;
        }
    }
    __syncthreads();
    const unsigned T = shT, ncand = shN;

    // ---- Scatter from LDS scores: pos = lds_base[b] + ticket(cnt)
    if (seg < 15) {
        unsigned* ch = cnt + h * NB;
        ull* Gh = G + (size_t)h * 65536;
        const int t_base = seg * 4096;
        for (int i = tid; i < 4096; i += 1024) {
            float v = s_lds[i];
            int b = bin_of(v, hi, sc);
            if ((unsigned)b <= T) {
                unsigned pos = lh[b] + atomicAdd(&ch[b], 1u);
                ST_A(&Gh[pos], ((ull)desc_key(v) << 16) | (unsigned)(t_base + i));
            }
        }
    }
    arrive(flag, 3); wait_head(flag, 3, h);

    // ---- Phase F: exact rank (static bin bounds from LDS scan); store packed
    {
        ull* csl = (ull*)(smem + 49152);        // 1.5 KB, after lh
        if (tid < NCOMP) csl[tid] = 0ull;
        __syncthreads();
        const ull* Gh = G + (size_t)h * 65536;
        for (unsigned p = seg * 1024 + tid; p < ncand; p += 16384) {
            ull pk = Gh[p];
            unsigned u = (unsigned)(pk >> 16);
            float v = u_to_f(u);
            int b = bin_of(v, hi, sc);
            unsigned start = lh[b];
            unsigned end = (b == NB - 1) ? ncand : lh[b + 1];
            unsigned rank = start;
            for (unsigned j = start; j < end; ++j) rank += (Gh[j] < pk) ? 1u : 0u;
            if (rank < KEEP) {
                ST_A(&stokv[h * KEEP + rank], pk);
                long long f = llrintf(v * 16777216.f);
                atomicAdd(&csl[rank >> 6], (ull)f);
            }
        }
        __syncthreads();
        if (tid < NCOMP) {
            ull c = csl[tid];
            if (c) atomicAdd(&cs_fix[tid], c);
        }
    }
    arrive(flag, 4); wait_all(flag, 4);

    // ---- Phase H: top-32 (redundant/block) + partial softmax+PV (2 pairs/blk)
    {
        ull* key = (ull*)smem;                       // 2048 B
        unsigned* sel_l = (unsigned*)(smem + 2048);  // 128 B
        float* scm = (float*)(smem + 2176);          // 512 B (2x64)
        float* exb = (float*)(smem + 2688);          // 512 B (2x64)
        float* vbuf = (float*)(smem + 3200);         // 2 x 64 x 68 floats
        if (tid < 256) {
            long long v = (long long)cs_fix[tid];    // plain: first touch post-F
            ull bb = (ull)(v + (1ll << 45));
            key[tid] = (((1ull << 46) - bb) << 8) | (unsigned)tid;
        }
        __syncthreads();
        for (unsigned k = 2; k <= 256; k <<= 1) {
            for (unsigned j = k >> 1; j > 0; j >>= 1) {
                if (tid < 256) {
                    unsigned ixj = tid ^ j;
                    if (ixj > (unsigned)tid) {
                        ull a = key[tid], b = key[ixj];
                        bool up = ((tid & k) == 0);
                        if (up ? (a > b) : (a < b)) { key[tid] = b; key[ixj] = a; }
                    }
                }
                __syncthreads();
            }
        }
        if (tid < NSEL) sel_l[tid] = (unsigned)(key[tid] & 0xFFull);
        __syncthreads();

        int su = tid >> 9, sid = tid & 511;
        int p = bid * 2 + su;                    // 0..511; hh == bid>>4 == h
        int hh = p >> 5, ci = p & 31;
        int c = (int)sel_l[ci];
        int g = sid >> 3, q8 = sid & 7;
        int t; float sv;
        if (c < NCOMP) {
            ull pk = stokv[hh * KEEP + c * 64 + g];   // plain: head-local
            t = (int)(pk & 0xFFFFull);
            sv = u_to_f((unsigned)(pk >> 16));
        } else {
            int j = (c - NCOMP) * 64 + g;
            t = PAST + j;
            sv = s_win[hh * 4096 + j];                // plain: first touch
        }
        if (q8 == 0) scm[su * 64 + g] = sv * 0.125f;
        __syncthreads();
        float m = -1e30f;
        for (int j = 0; j < 64; ++j) m = fmaxf(m, scm[su * 64 + j]);
        float e = expf(scm[su * 64 + g] - m);
        if (q8 == 0) exb[su * 64 + g] = e;
        const float4* vrow = (const float4*)(vc + (size_t)t * C + hh * HS);
        float4 v0 = vrow[q8 * 2], v1 = vrow[q8 * 2 + 1];
        float* vb = vbuf + su * 4352 + g * 68 + q8 * 8;
        vb[0] = e * v0.x; vb[1] = e * v0.y; vb[2] = e * v0.z; vb[3] = e * v0.w;
        vb[4] = e * v1.x; vb[5] = e * v1.y; vb[6] = e * v1.z; vb[7] = e * v1.w;
        __syncthreads();
        if (sid < 64) {
            float acc = 0.f;
            for (int g2 = 0; g2 < 64; ++g2) acc += vbuf[su * 4352 + g2 * 68 + sid];
            float* P = part + (size_t)(hh * 32 + ci) * 68;
            ST_A(&P[2 + sid], acc);
            if (sid == 0) {
                float es = 0.f;
                for (int g2 = 0; g2 < 64; ++g2) es += exb[su * 64 + g2];
                ST_A(&P[0], m);
                ST_A(&P[1], es);
            }
        }
    }
    arrive(flag, 5); wait_head(flag, 5, h);

    // ---- Wo prefetch (independent of y) hides under the y barrier
    int row = bid * 4 + (wave >> 2), qtr = wave & 3;
    const float4* Wrow4 = (const float4*)(Wo + (size_t)row * C) + qtr * 64;
    float4 wa = Wrow4[lane];

    // ---- y[h]: combined once per head (seg 0), 64 lanes
    if (seg == 0 && tid < 64) {
        float p = q[h * 64 + tid] * kn[h * 64 + tid];
#pragma unroll
        for (int off = 32; off; off >>= 1) p += __shfl_xor(p, off);
        float a_new = p * 0.125f;
        const float* P0 = part + (size_t)h * 32 * 68;   // plain: head-local
        float m = a_new;
        for (int ci = 0; ci < 32; ++ci) m = fmaxf(m, P0[ci * 68]);
        float den = expf(a_new - m);
        float acc = den * vn[h * HS + tid];
        for (int ci = 0; ci < 32; ++ci) {
            float w = expf(P0[ci * 68] - m);
            den += w * P0[ci * 68 + 1];
            acc += w * P0[ci * 68 + 2 + tid];
        }
        ST_A(&yg[h * HS + tid], acc / den);
    }
    if (seg == 0) arrive(flag, 6);             // only y-writers publish phase 6
    if (tid < 16)
        while (LD_A(&flag[(tid * 16) * FLAGW]) < 6u) __builtin_amdgcn_s_sleep(2);
    __syncthreads();

    // ---- Wo matmul: block bid -> rows [bid*4, bid*4+4), wave = (row, quarter)
    {
        float* yl = (float*)smem;                 // 4 KB
        float* ps = (float*)(smem + 4096);        // 64 B
        yl[tid] = yg[tid];                        // plain: first touch this block
        __syncthreads();
        const float4* y4 = (const float4*)yl + qtr * 64;
        float4 b = y4[lane];
        float acc = wa.x * b.x + wa.y * b.y + wa.z * b.z + wa.w * b.w;
#pragma unroll
        for (int off = 32; off; off >>= 1) acc += __shfl_xor(acc, off);
        if (lane == 0) ps[wave] = acc;
        __syncthreads();
        if (tid < 4)
            out[bid * 4 + tid] = ps[tid * 4] + ps[tid * 4 + 1] + ps[tid * 4 + 2] + ps[tid * 4 + 3];
    }
}

extern "C" void kernel_launch(void* const* d_in, const int* in_sizes, int n_in,
                              void* d_out, int out_size, void* d_ws, size_t ws_size,
                              hipStream_t stream) {
    const float* x  = (const float*)d_in[0];
    const float* kc = (const float*)d_in[1];
    const float* vc = (const float*)d_in[2];
    const float* Wr = (const float*)d_in[3];
    const float* Wk = (const float*)d_in[4];
    const float* Wv = (const float*)d_in[5];
    const float* Wo = (const float*)d_in[6];
    float* out = (float*)d_out;
    char* ws = (char*)d_ws;

    float* q    = (float*)(ws + 0);
    float* kn   = (float*)(ws + 8192);
    float* vn   = (float*)(ws + 16384);
    ull* cs_fix = (ull*)(ws + 32768);                  // 2 KiB
    float* yg   = (float*)(ws + 40960);                // 4 KiB
    float* part = (float*)(ws + 49152);                // 139264 B -> ends 188416
    unsigned* umin = (unsigned*)(ws + 188416);
    unsigned* umax = (unsigned*)(ws + 188480);
    unsigned* flag = (unsigned*)(ws + 192512);         // 8 KiB (256 x 32B)
    float* s_win   = (float*)(ws + 262144);            // 256 KiB -> ends 524288
    ull* stokv     = (ull*)(ws + 524288);              // 1.5 MiB -> ends 2097152
    unsigned* hist = (unsigned*)(ws + 2097152);        // 512 KiB
    unsigned* cnt  = (unsigned*)(ws + 2621440);        // 512 KiB (contiguous after hist)
    ull* G = (ull*)(ws + 3145728);                     // 8 MiB

    k_proj<<<768, 256, 0, stream>>>(x, Wr, Wk, Wv, q, kn, vn, hist, umin, umax, cs_fix, flag);
    k_mega<<<NBLK, 1024, 0, stream>>>(kc, vc, umin, umax, hist, cnt, G, stokv, cs_fix,
                                      part, q, kn, vn, Wo, yg, out, s_win, flag);
}